// Round 4
// baseline (2095.175 us; speedup 1.0000x reference)
//
#include <hip/hip_runtime.h>

#define N0c 262144
#define INc 128
#define Hc  32
#define N1c 131072
#define N2c 65536
#define E0c 2097152
#define E1c 1048576

__device__ __forceinline__ void fma4(float4& a, float s, const float4 w) {
    a.x = fmaf(s, w.x, a.x);
    a.y = fmaf(s, w.y, a.y);
    a.z = fmaf(s, w.z, a.z);
    a.w = fmaf(s, w.w, a.w);
}

// ---------------- layer-0 linear: y = x @ wl^T (all N0 rows), z = x @ wr^T (rows < N1) ----
// 256 threads, 128 rows/block, K=128 staged in 4 chunks of 32.
// LDS 24 KB -> 5 blocks/CU (20 waves/CU) vs old 64 KB (1 wave/SIMD).
__global__ __launch_bounds__(256, 5) void lin0_kernel(
    const float* __restrict__ x, const float* __restrict__ wl,
    const float* __restrict__ wr, float* __restrict__ y, float* __restrict__ z)
{
    __shared__ float xs[128 * 32];     // 16 KB, [row][k-chunk] swizzled
    __shared__ float wls[32 * 32];     //  4 KB, [k][j] swizzled
    __shared__ float wrs[32 * 32];     //  4 KB
    const int t = threadIdx.x;
    const int rowBase = blockIdx.x * 128;
    const bool doZ = rowBase < N1c;
    const int cg = t & 7;              // col group (4 cols)
    const int rg = t >> 3;             // row group (4 rows), 0..31

    float4* xs4w = (float4*)xs;
    const float4* xs4  = (const float4*)xs;
    const float4* wls4 = (const float4*)wls;
    const float4* wrs4 = (const float4*)wrs;

    float4 accY[4], accZ[4];
#pragma unroll
    for (int i = 0; i < 4; ++i) {
        accY[i] = make_float4(0.f, 0.f, 0.f, 0.f);
        accZ[i] = make_float4(0.f, 0.f, 0.f, 0.f);
    }

    for (int kc = 0; kc < 4; ++kc) {
        if (kc) __syncthreads();
        // stage x chunk: 128 rows x 8 float4, 4 per thread; rotate quad by row>>2
#pragma unroll
        for (int i = 0; i < 4; ++i) {
            int idx = t + 256 * i;
            int row = idx >> 3, kq = idx & 7;
            float4 v = ((const float4*)x)[(rowBase + row) * 32 + kc * 8 + kq];
            xs4w[row * 8 + ((kq + (row >> 2)) & 7)] = v;
        }
        // stage weight chunks: 32 k x 32 j each, 4 per thread
#pragma unroll
        for (int i = 0; i < 4; ++i) {
            int idx = t + 256 * i;
            int kk = idx & 31, j = idx >> 5;
            int dst = kk * 32 + 4 * (((j >> 2) + kk) & 7) + (j & 3);
            float a = wl[j * 128 + kc * 32 + kk];
            wls[dst] = a;
            if (doZ) wrs[dst] = wr[j * 128 + kc * 32 + kk];
        }
        __syncthreads();

#pragma unroll
        for (int kq = 0; kq < 8; ++kq) {
            float4 xv[4];
#pragma unroll
            for (int i = 0; i < 4; ++i)
                xv[i] = xs4[(4 * rg + i) * 8 + ((kq + rg) & 7)];
            const int kb = 4 * kq;
            float4 w0 = wls4[(kb + 0) * 8 + ((cg + kb + 0) & 7)];
            float4 w1 = wls4[(kb + 1) * 8 + ((cg + kb + 1) & 7)];
            float4 w2 = wls4[(kb + 2) * 8 + ((cg + kb + 2) & 7)];
            float4 w3 = wls4[(kb + 3) * 8 + ((cg + kb + 3) & 7)];
#pragma unroll
            for (int i = 0; i < 4; ++i) {
                fma4(accY[i], xv[i].x, w0);
                fma4(accY[i], xv[i].y, w1);
                fma4(accY[i], xv[i].z, w2);
                fma4(accY[i], xv[i].w, w3);
            }
            if (doZ) {
                float4 u0 = wrs4[(kb + 0) * 8 + ((cg + kb + 0) & 7)];
                float4 u1 = wrs4[(kb + 1) * 8 + ((cg + kb + 1) & 7)];
                float4 u2 = wrs4[(kb + 2) * 8 + ((cg + kb + 2) & 7)];
                float4 u3 = wrs4[(kb + 3) * 8 + ((cg + kb + 3) & 7)];
#pragma unroll
                for (int i = 0; i < 4; ++i) {
                    fma4(accZ[i], xv[i].x, u0);
                    fma4(accZ[i], xv[i].y, u1);
                    fma4(accZ[i], xv[i].z, u2);
                    fma4(accZ[i], xv[i].w, u3);
                }
            }
        }
    }

#pragma unroll
    for (int i = 0; i < 4; ++i) {
        int r = rowBase + 4 * rg + i;
        ((float4*)y)[r * 8 + cg] = accY[i];
        if (doZ) ((float4*)z)[r * 8 + cg] = accZ[i];
    }
}

// ---------------- layer-1 linear: K=32, 64 rows/block ----------------
__global__ __launch_bounds__(128) void lin1_kernel(
    const float* __restrict__ h, const float* __restrict__ wl,
    const float* __restrict__ wr, float* __restrict__ y, float* __restrict__ z)
{
    __shared__ float xs[64 * 32];
    __shared__ float wls[32 * 32];
    __shared__ float wrs[32 * 32];
    const int t = threadIdx.x;
    const long rowBase = (long)blockIdx.x * 64;
    const bool doZ = rowBase < N2c;

#pragma unroll
    for (int i = 0; i < 8; ++i) {
        int idx = t + 128 * i;          // = j*32 + k
        int j = idx >> 5, k = idx & 31;
        int dst = k * 32 + 4 * (((j >> 2) + k) & 7) + (j & 3);
        wls[dst] = wl[idx];
        if (doZ) wrs[dst] = wr[idx];
    }
#pragma unroll
    for (int i = 0; i < 4; ++i) {
        int idx = t + 128 * i;          // float4 idx 0..511
        int row = idx >> 3, k4 = idx & 7;
        float4 v = ((const float4*)h)[rowBase * 8 + idx];
        ((float4*)xs)[row * 8 + ((k4 + (row >> 2)) & 7)] = v;
    }
    __syncthreads();

    const int cg = t & 7;
    const int rg = t >> 3;
    const float4* xs4  = (const float4*)xs;
    const float4* wls4 = (const float4*)wls;
    const float4* wrs4 = (const float4*)wrs;

    float4 accY[4], accZ[4];
#pragma unroll
    for (int i = 0; i < 4; ++i) {
        accY[i] = make_float4(0.f, 0.f, 0.f, 0.f);
        accZ[i] = make_float4(0.f, 0.f, 0.f, 0.f);
    }

#pragma unroll
    for (int k4 = 0; k4 < 8; ++k4) {
        float4 xv[4];
#pragma unroll
        for (int i = 0; i < 4; ++i)
            xv[i] = xs4[(4 * rg + i) * 8 + ((k4 + rg) & 7)];
        const int kb = 4 * k4;
        float4 w0 = wls4[(kb + 0) * 8 + ((cg + kb + 0) & 7)];
        float4 w1 = wls4[(kb + 1) * 8 + ((cg + kb + 1) & 7)];
        float4 w2 = wls4[(kb + 2) * 8 + ((cg + kb + 2) & 7)];
        float4 w3 = wls4[(kb + 3) * 8 + ((cg + kb + 3) & 7)];
#pragma unroll
        for (int i = 0; i < 4; ++i) {
            fma4(accY[i], xv[i].x, w0);
            fma4(accY[i], xv[i].y, w1);
            fma4(accY[i], xv[i].z, w2);
            fma4(accY[i], xv[i].w, w3);
        }
        if (doZ) {
            float4 u0 = wrs4[(kb + 0) * 8 + ((cg + kb + 0) & 7)];
            float4 u1 = wrs4[(kb + 1) * 8 + ((cg + kb + 1) & 7)];
            float4 u2 = wrs4[(kb + 2) * 8 + ((cg + kb + 2) & 7)];
            float4 u3 = wrs4[(kb + 3) * 8 + ((cg + kb + 3) & 7)];
#pragma unroll
            for (int i = 0; i < 4; ++i) {
                fma4(accZ[i], xv[i].x, u0);
                fma4(accZ[i], xv[i].y, u1);
                fma4(accZ[i], xv[i].z, u2);
                fma4(accZ[i], xv[i].w, u3);
            }
        }
    }
#pragma unroll
    for (int i = 0; i < 4; ++i) {
        long r = rowBase + 4 * rg + i;
        ((float4*)y)[r * 8 + cg] = accY[i];
        if (doZ) ((float4*)z)[r * 8 + cg] = accZ[i];
    }
}

// ---------------- CSR build: per-target histogram ----------------
__global__ __launch_bounds__(256) void hist_kernel(
    const int* __restrict__ tgt, int* __restrict__ cnt, int nE)
{
    int e = blockIdx.x * 256 + threadIdx.x;
    if (e < nE) atomicAdd(&cnt[tgt[e]], 1);
}

// ---------------- CSR build: 2-level exclusive scan ----------------
__global__ __launch_bounds__(256) void scanA_kernel(
    const int* __restrict__ cnt, int* __restrict__ cursor, int* __restrict__ bsum)
{
    __shared__ int s[256];
    int t = threadIdx.x;
    int base = blockIdx.x * 512;
    int c0 = cnt[base + 2 * t];
    int c1 = cnt[base + 2 * t + 1];
    int local = c0 + c1;
    s[t] = local;
    __syncthreads();
    int v = local;
#pragma unroll
    for (int off = 1; off < 256; off <<= 1) {
        int u = (t >= off) ? s[t - off] : 0;
        __syncthreads();
        v += u;
        s[t] = v;
        __syncthreads();
    }
    int ex = v - local;
    cursor[base + 2 * t]     = ex;
    cursor[base + 2 * t + 1] = ex + c0;
    if (t == 255) bsum[blockIdx.x] = v;
}

__global__ __launch_bounds__(256) void scanB_kernel(int* __restrict__ bsum, int nb)
{
    __shared__ int s[256];
    int t = threadIdx.x;
    int local = (t < nb) ? bsum[t] : 0;
    s[t] = local;
    __syncthreads();
    int v = local;
#pragma unroll
    for (int off = 1; off < 256; off <<= 1) {
        int u = (t >= off) ? s[t - off] : 0;
        __syncthreads();
        v += u;
        s[t] = v;
        __syncthreads();
    }
    if (t < nb) bsum[t] = v - local;
}

// scanC: add block offsets; also emit per-bucket (512-target group) base cursors
__global__ __launch_bounds__(256) void scanC_kernel(
    int* __restrict__ cursor, const int* __restrict__ bsum, int* __restrict__ bcur)
{
    int i = blockIdx.x * 256 + threadIdx.x;
    int v = cursor[i] + bsum[i >> 9];
    cursor[i] = v;
    if ((i & 511) == 0) bcur[i >> 9] = v;
}

// ---------------- partition pass 1: multisplit into 512-target buckets ----------------
__global__ __launch_bounds__(256) void part_kernel(
    const int* __restrict__ src, const int* __restrict__ tgt,
    int2* __restrict__ pairs, int* __restrict__ bcur, int nb)
{
    __shared__ int hist[256];
    __shared__ int bbase[256];
    const int t = threadIdx.x;
    const int base = blockIdx.x * 8192;
    hist[t] = 0;
    __syncthreads();
#pragma unroll 4
    for (int i = 0; i < 32; ++i) {
        int e = base + i * 256 + t;
        atomicAdd(&hist[tgt[e] >> 9], 1);
    }
    __syncthreads();
    if (t < nb) bbase[t] = atomicAdd(&bcur[t], hist[t]);
    __syncthreads();
    hist[t] = 0;
    __syncthreads();
#pragma unroll 4
    for (int i = 0; i < 32; ++i) {
        int e = base + i * 256 + t;
        int tv = tgt[e], sv = src[e];
        int b = tv >> 9;
        int r = atomicAdd(&hist[b], 1);
        pairs[bbase[b] + r] = make_int2(sv, tv);
    }
}

// ---------------- partition pass 2: bucket-local rank -> eidx ----------------
__global__ __launch_bounds__(512) void sortb_kernel(
    const int2* __restrict__ pairs, const int* __restrict__ cur,
    int* __restrict__ eidx, int nT, int nE)
{
    __shared__ int lrank[512];
    const int b = blockIdx.x;
    const int t = threadIdx.x;
    lrank[t] = 0;
    __syncthreads();
    const int tlo = b << 9;
    const int beg = cur[tlo];
    const int thi = tlo + 512;
    const int end = (thi < nT) ? cur[thi] : nE;
    for (int e = beg + t; e < end; e += 512) {
        int2 p = pairs[e];
        int r = atomicAdd(&lrank[p.y - tlo], 1);
        eidx[cur[p.y] + r] = p.x;
    }
}

// ---------------- gather-reduce + fused epilogue ----------------
__global__ __launch_bounds__(256) void gather_agg_kernel(
    const float* __restrict__ yv, const int* __restrict__ eidx,
    const int* __restrict__ cnt, const int* __restrict__ cur,
    const float* __restrict__ z, const float* __restrict__ b,
    float* __restrict__ out, int n, int doRelu)
{
    int t = blockIdx.x * 256 + threadIdx.x;
    int row = t >> 3, part = t & 7;
    if (row >= n) return;
    int c = cnt[row];
    int beg = cur[row];
    int end = beg + c;
    const float4* y4 = (const float4*)yv;
    float4 acc = make_float4(0.f, 0.f, 0.f, 0.f);
    int e = beg;
    for (; e + 1 < end; e += 2) {
        int s0 = eidx[e], s1 = eidx[e + 1];
        float4 v0 = y4[(long)s0 * 8 + part];
        float4 v1 = y4[(long)s1 * 8 + part];
        acc.x += v0.x + v1.x;
        acc.y += v0.y + v1.y;
        acc.z += v0.z + v1.z;
        acc.w += v0.w + v1.w;
    }
    if (e < end) {
        int s0 = eidx[e];
        float4 v0 = y4[(long)s0 * 8 + part];
        acc.x += v0.x; acc.y += v0.y; acc.z += v0.z; acc.w += v0.w;
    }
    float inv = 1.f / fmaxf((float)c, 1.f);
    float4 bb = ((const float4*)b)[part];
    float4 zz = ((const float4*)z)[(long)row * 8 + part];
    float4 v;
    v.x = fmaf(acc.x, inv, bb.x) + zz.x;
    v.y = fmaf(acc.y, inv, bb.y) + zz.y;
    v.z = fmaf(acc.z, inv, bb.z) + zz.z;
    v.w = fmaf(acc.w, inv, bb.w) + zz.w;
    float ss = v.x * v.x + v.y * v.y + v.z * v.z + v.w * v.w;
    ss += __shfl_xor(ss, 1);
    ss += __shfl_xor(ss, 2);
    ss += __shfl_xor(ss, 4);
    float q = 1.f / fmaxf(sqrtf(ss), 1e-12f);
    v.x *= q; v.y *= q; v.z *= q; v.w *= q;
    if (doRelu) {
        v.x = fmaxf(v.x, 0.f); v.y = fmaxf(v.y, 0.f);
        v.z = fmaxf(v.z, 0.f); v.w = fmaxf(v.w, 0.f);
    }
    ((float4*)out)[(long)row * 8 + part] = v;
}

extern "C" void kernel_launch(void* const* d_in, const int* in_sizes, int n_in,
                              void* d_out, int out_size, void* d_ws, size_t ws_size,
                              hipStream_t stream) {
    const float* x   = (const float*)d_in[0];
    const int* src0  = (const int*)d_in[1];
    const int* tgt0  = (const int*)d_in[2];
    const int* src1  = (const int*)d_in[3];
    const int* tgt1  = (const int*)d_in[4];
    const float* wl0 = (const float*)d_in[5];
    const float* bl0 = (const float*)d_in[6];
    const float* wr0 = (const float*)d_in[7];
    const float* wl1 = (const float*)d_in[8];
    const float* bl1 = (const float*)d_in[9];
    const float* wr1 = (const float*)d_in[10];

    char* W = (char*)d_ws;
    // region A [0,32M): y0; after gather0 reused for layer-1 buffers
    float* y0    = (float*)(W + 0);             // 32 MB
    float* y1    = (float*)(W + 0);             // 16 MB
    float* z1    = (float*)(W + 16777216);      //  8 MB
    int*   eidx1 = (int*)  (W + 25165824);      //  4 MB
    int*   cnt1  = (int*)  (W + 29360128);      // 256 KB
    int*   cur1  = (int*)  (W + 29622272);      // 256 KB
    // region B [32M,48M): z0; after gather0 reused for pairs1 (8 MB)
    float* z0    = (float*)(W + 33554432);      // 16 MB
    int2*  pairs1= (int2*) (W + 33554432);      //  8 MB
    // region C [48M,64M): pairs0 (live P1->P2), then h (written by gather0 after P2)
    int2*  pairs0= (int2*) (W + 50331648);      // 16 MB
    float* h     = (float*)(W + 50331648);      // 16 MB
    // region D [64M,72M): eidx0
    int*   eidx0 = (int*)  (W + 67108864);      //  8 MB
    // region E [72M,...): cnt0, cur0, bsum, bcur
    int*   cnt0  = (int*)  (W + 75497472);      // 512 KB
    int*   cur0  = (int*)  (W + 76021760);      // 512 KB
    int*   bsum  = (int*)  (W + 76546048);      //  1 KB
    int*   bcur  = (int*)  (W + 76547072);      //  1 KB

    // ---- layer 0 ----
    hipMemsetAsync(cnt0, 0, 524288, stream);
    lin0_kernel<<<N0c / 128, 256, 0, stream>>>(x, wl0, wr0, y0, z0);
    hist_kernel<<<E0c / 256, 256, 0, stream>>>(tgt0, cnt0, E0c);
    scanA_kernel<<<N1c / 512, 256, 0, stream>>>(cnt0, cur0, bsum);
    scanB_kernel<<<1, 256, 0, stream>>>(bsum, N1c / 512);
    scanC_kernel<<<N1c / 256, 256, 0, stream>>>(cur0, bsum, bcur);
    part_kernel<<<E0c / 8192, 256, 0, stream>>>(src0, tgt0, pairs0, bcur, 256);
    sortb_kernel<<<N1c / 512, 512, 0, stream>>>(pairs0, cur0, eidx0, N1c, E0c);
    gather_agg_kernel<<<(N1c * 8) / 256, 256, 0, stream>>>(y0, eidx0, cnt0, cur0,
                                                           z0, bl0, h, N1c, 1);

    // ---- layer 1 (y0/z0 dead; regions A/B reused) ----
    hipMemsetAsync(cnt1, 0, 262144, stream);
    hist_kernel<<<E1c / 256, 256, 0, stream>>>(tgt1, cnt1, E1c);
    scanA_kernel<<<N2c / 512, 256, 0, stream>>>(cnt1, cur1, bsum);
    scanB_kernel<<<1, 256, 0, stream>>>(bsum, N2c / 512);
    scanC_kernel<<<N2c / 256, 256, 0, stream>>>(cur1, bsum, bcur);
    part_kernel<<<E1c / 8192, 256, 0, stream>>>(src1, tgt1, pairs1, bcur, 128);
    lin1_kernel<<<N1c / 64, 128, 0, stream>>>(h, wl1, wr1, y1, z1);
    sortb_kernel<<<N2c / 512, 512, 0, stream>>>(pairs1, cur1, eidx1, N2c, E1c);
    gather_agg_kernel<<<(N2c * 8) / 256, 256, 0, stream>>>(y1, eidx1, cnt1, cur1,
                                                           z1, bl1, (float*)d_out, N2c, 0);
}

// Round 5
// 1805.714 us; speedup vs baseline: 1.1603x; 1.1603x over previous
//
#include <hip/hip_runtime.h>

#define N0c 262144
#define INc 128
#define Hc  32
#define N1c 131072
#define N2c 65536
#define E0c 2097152
#define E1c 1048576

__device__ __forceinline__ void fma4(float4& a, float s, const float4 w) {
    a.x = fmaf(s, w.x, a.x);
    a.y = fmaf(s, w.y, a.y);
    a.z = fmaf(s, w.z, a.z);
    a.w = fmaf(s, w.w, a.w);
}

// ---------------- layer-0 linear: y = x @ wl^T (all N0 rows), z = x @ wr^T (rows < N1) ----
// 256 threads, 128 rows/block, K=128 staged in 4 chunks of 32. LDS 24 KB.
// __launch_bounds__(256,3): cap ~168 VGPR -> NO SPILL (round-4's (256,5) forced
// VGPR=48 and spilled 5.5 GB to scratch). Actual occupancy set by real VGPR use.
__global__ __launch_bounds__(256, 3) void lin0_kernel(
    const float* __restrict__ x, const float* __restrict__ wl,
    const float* __restrict__ wr, float* __restrict__ y, float* __restrict__ z)
{
    __shared__ float xs[128 * 32];     // 16 KB, [row][k-chunk] swizzled
    __shared__ float wls[32 * 32];     //  4 KB, [k][j] swizzled
    __shared__ float wrs[32 * 32];     //  4 KB
    const int t = threadIdx.x;
    const int rowBase = blockIdx.x * 128;
    const bool doZ = rowBase < N1c;
    const int cg = t & 7;              // col group (4 cols)
    const int rg = t >> 3;             // row group (4 rows), 0..31

    float4* xs4w = (float4*)xs;
    const float4* xs4  = (const float4*)xs;
    const float4* wls4 = (const float4*)wls;
    const float4* wrs4 = (const float4*)wrs;

    float4 accY[4], accZ[4];
#pragma unroll
    for (int i = 0; i < 4; ++i) {
        accY[i] = make_float4(0.f, 0.f, 0.f, 0.f);
        accZ[i] = make_float4(0.f, 0.f, 0.f, 0.f);
    }

    for (int kc = 0; kc < 4; ++kc) {
        if (kc) __syncthreads();
        // stage x chunk: 128 rows x 8 float4, 4 per thread; rotate quad by row>>2
#pragma unroll
        for (int i = 0; i < 4; ++i) {
            int idx = t + 256 * i;
            int row = idx >> 3, kq = idx & 7;
            float4 v = ((const float4*)x)[(rowBase + row) * 32 + kc * 8 + kq];
            xs4w[row * 8 + ((kq + (row >> 2)) & 7)] = v;
        }
        // stage weight chunks: 32 k x 32 j each, 4 per thread
#pragma unroll
        for (int i = 0; i < 4; ++i) {
            int idx = t + 256 * i;
            int kk = idx & 31, j = idx >> 5;
            int dst = kk * 32 + 4 * (((j >> 2) + kk) & 7) + (j & 3);
            float a = wl[j * 128 + kc * 32 + kk];
            wls[dst] = a;
            if (doZ) wrs[dst] = wr[j * 128 + kc * 32 + kk];
        }
        __syncthreads();

#pragma unroll
        for (int kq = 0; kq < 8; ++kq) {
            float4 xv[4];
#pragma unroll
            for (int i = 0; i < 4; ++i)
                xv[i] = xs4[(4 * rg + i) * 8 + ((kq + rg) & 7)];
            const int kb = 4 * kq;
            float4 w0 = wls4[(kb + 0) * 8 + ((cg + kb + 0) & 7)];
            float4 w1 = wls4[(kb + 1) * 8 + ((cg + kb + 1) & 7)];
            float4 w2 = wls4[(kb + 2) * 8 + ((cg + kb + 2) & 7)];
            float4 w3 = wls4[(kb + 3) * 8 + ((cg + kb + 3) & 7)];
#pragma unroll
            for (int i = 0; i < 4; ++i) {
                fma4(accY[i], xv[i].x, w0);
                fma4(accY[i], xv[i].y, w1);
                fma4(accY[i], xv[i].z, w2);
                fma4(accY[i], xv[i].w, w3);
            }
            if (doZ) {
                float4 u0 = wrs4[(kb + 0) * 8 + ((cg + kb + 0) & 7)];
                float4 u1 = wrs4[(kb + 1) * 8 + ((cg + kb + 1) & 7)];
                float4 u2 = wrs4[(kb + 2) * 8 + ((cg + kb + 2) & 7)];
                float4 u3 = wrs4[(kb + 3) * 8 + ((cg + kb + 3) & 7)];
#pragma unroll
                for (int i = 0; i < 4; ++i) {
                    fma4(accZ[i], xv[i].x, u0);
                    fma4(accZ[i], xv[i].y, u1);
                    fma4(accZ[i], xv[i].z, u2);
                    fma4(accZ[i], xv[i].w, u3);
                }
            }
        }
    }

#pragma unroll
    for (int i = 0; i < 4; ++i) {
        int r = rowBase + 4 * rg + i;
        ((float4*)y)[r * 8 + cg] = accY[i];
        if (doZ) ((float4*)z)[r * 8 + cg] = accZ[i];
    }
}

// ---------------- layer-1 linear: K=32, 64 rows/block ----------------
__global__ __launch_bounds__(128) void lin1_kernel(
    const float* __restrict__ h, const float* __restrict__ wl,
    const float* __restrict__ wr, float* __restrict__ y, float* __restrict__ z)
{
    __shared__ float xs[64 * 32];
    __shared__ float wls[32 * 32];
    __shared__ float wrs[32 * 32];
    const int t = threadIdx.x;
    const long rowBase = (long)blockIdx.x * 64;
    const bool doZ = rowBase < N2c;

#pragma unroll
    for (int i = 0; i < 8; ++i) {
        int idx = t + 128 * i;          // = j*32 + k
        int j = idx >> 5, k = idx & 31;
        int dst = k * 32 + 4 * (((j >> 2) + k) & 7) + (j & 3);
        wls[dst] = wl[idx];
        if (doZ) wrs[dst] = wr[idx];
    }
#pragma unroll
    for (int i = 0; i < 4; ++i) {
        int idx = t + 128 * i;          // float4 idx 0..511
        int row = idx >> 3, k4 = idx & 7;
        float4 v = ((const float4*)h)[rowBase * 8 + idx];
        ((float4*)xs)[row * 8 + ((k4 + (row >> 2)) & 7)] = v;
    }
    __syncthreads();

    const int cg = t & 7;
    const int rg = t >> 3;
    const float4* xs4  = (const float4*)xs;
    const float4* wls4 = (const float4*)wls;
    const float4* wrs4 = (const float4*)wrs;

    float4 accY[4], accZ[4];
#pragma unroll
    for (int i = 0; i < 4; ++i) {
        accY[i] = make_float4(0.f, 0.f, 0.f, 0.f);
        accZ[i] = make_float4(0.f, 0.f, 0.f, 0.f);
    }

#pragma unroll
    for (int k4 = 0; k4 < 8; ++k4) {
        float4 xv[4];
#pragma unroll
        for (int i = 0; i < 4; ++i)
            xv[i] = xs4[(4 * rg + i) * 8 + ((k4 + rg) & 7)];
        const int kb = 4 * k4;
        float4 w0 = wls4[(kb + 0) * 8 + ((cg + kb + 0) & 7)];
        float4 w1 = wls4[(kb + 1) * 8 + ((cg + kb + 1) & 7)];
        float4 w2 = wls4[(kb + 2) * 8 + ((cg + kb + 2) & 7)];
        float4 w3 = wls4[(kb + 3) * 8 + ((cg + kb + 3) & 7)];
#pragma unroll
        for (int i = 0; i < 4; ++i) {
            fma4(accY[i], xv[i].x, w0);
            fma4(accY[i], xv[i].y, w1);
            fma4(accY[i], xv[i].z, w2);
            fma4(accY[i], xv[i].w, w3);
        }
        if (doZ) {
            float4 u0 = wrs4[(kb + 0) * 8 + ((cg + kb + 0) & 7)];
            float4 u1 = wrs4[(kb + 1) * 8 + ((cg + kb + 1) & 7)];
            float4 u2 = wrs4[(kb + 2) * 8 + ((cg + kb + 2) & 7)];
            float4 u3 = wrs4[(kb + 3) * 8 + ((cg + kb + 3) & 7)];
#pragma unroll
            for (int i = 0; i < 4; ++i) {
                fma4(accZ[i], xv[i].x, u0);
                fma4(accZ[i], xv[i].y, u1);
                fma4(accZ[i], xv[i].z, u2);
                fma4(accZ[i], xv[i].w, u3);
            }
        }
    }
#pragma unroll
    for (int i = 0; i < 4; ++i) {
        long r = rowBase + 4 * rg + i;
        ((float4*)y)[r * 8 + cg] = accY[i];
        if (doZ) ((float4*)z)[r * 8 + cg] = accZ[i];
    }
}

// ---------------- CSR build: per-target histogram ----------------
__global__ __launch_bounds__(256) void hist_kernel(
    const int* __restrict__ tgt, int* __restrict__ cnt, int nE)
{
    int e = blockIdx.x * 256 + threadIdx.x;
    if (e < nE) atomicAdd(&cnt[tgt[e]], 1);
}

// ---------------- CSR build: 2-level exclusive scan ----------------
__global__ __launch_bounds__(256) void scanA_kernel(
    const int* __restrict__ cnt, int* __restrict__ cursor, int* __restrict__ bsum)
{
    __shared__ int s[256];
    int t = threadIdx.x;
    int base = blockIdx.x * 512;
    int c0 = cnt[base + 2 * t];
    int c1 = cnt[base + 2 * t + 1];
    int local = c0 + c1;
    s[t] = local;
    __syncthreads();
    int v = local;
#pragma unroll
    for (int off = 1; off < 256; off <<= 1) {
        int u = (t >= off) ? s[t - off] : 0;
        __syncthreads();
        v += u;
        s[t] = v;
        __syncthreads();
    }
    int ex = v - local;
    cursor[base + 2 * t]     = ex;
    cursor[base + 2 * t + 1] = ex + c0;
    if (t == 255) bsum[blockIdx.x] = v;
}

__global__ __launch_bounds__(256) void scanB_kernel(int* __restrict__ bsum, int nb)
{
    __shared__ int s[256];
    int t = threadIdx.x;
    int local = (t < nb) ? bsum[t] : 0;
    s[t] = local;
    __syncthreads();
    int v = local;
#pragma unroll
    for (int off = 1; off < 256; off <<= 1) {
        int u = (t >= off) ? s[t - off] : 0;
        __syncthreads();
        v += u;
        s[t] = v;
        __syncthreads();
    }
    if (t < nb) bsum[t] = v - local;
}

// scanC: add block offsets; also emit per-bucket (512-target group) base cursors
__global__ __launch_bounds__(256) void scanC_kernel(
    int* __restrict__ cursor, const int* __restrict__ bsum, int* __restrict__ bcur)
{
    int i = blockIdx.x * 256 + threadIdx.x;
    int v = cursor[i] + bsum[i >> 9];
    cursor[i] = v;
    if ((i & 511) == 0) bcur[i >> 9] = v;
}

// ---------------- partition pass 1: multisplit into 512-target buckets ----------------
__global__ __launch_bounds__(256) void part_kernel(
    const int* __restrict__ src, const int* __restrict__ tgt,
    int2* __restrict__ pairs, int* __restrict__ bcur, int nb)
{
    __shared__ int hist[256];
    __shared__ int bbase[256];
    const int t = threadIdx.x;
    const int base = blockIdx.x * 8192;
    hist[t] = 0;
    __syncthreads();
#pragma unroll 4
    for (int i = 0; i < 32; ++i) {
        int e = base + i * 256 + t;
        atomicAdd(&hist[tgt[e] >> 9], 1);
    }
    __syncthreads();
    if (t < nb) bbase[t] = atomicAdd(&bcur[t], hist[t]);
    __syncthreads();
    hist[t] = 0;
    __syncthreads();
#pragma unroll 4
    for (int i = 0; i < 32; ++i) {
        int e = base + i * 256 + t;
        int tv = tgt[e], sv = src[e];
        int b = tv >> 9;
        int r = atomicAdd(&hist[b], 1);
        pairs[bbase[b] + r] = make_int2(sv, tv);
    }
}

// ---------------- partition pass 2: bucket-local rank -> eidx ----------------
__global__ __launch_bounds__(512) void sortb_kernel(
    const int2* __restrict__ pairs, const int* __restrict__ cur,
    int* __restrict__ eidx, int nT, int nE)
{
    __shared__ int lrank[512];
    const int b = blockIdx.x;
    const int t = threadIdx.x;
    lrank[t] = 0;
    __syncthreads();
    const int tlo = b << 9;
    const int beg = cur[tlo];
    const int thi = tlo + 512;
    const int end = (thi < nT) ? cur[thi] : nE;
    for (int e = beg + t; e < end; e += 512) {
        int2 p = pairs[e];
        int r = atomicAdd(&lrank[p.y - tlo], 1);
        eidx[cur[p.y] + r] = p.x;
    }
}

// ---------------- gather-reduce + fused epilogue ----------------
__global__ __launch_bounds__(256) void gather_agg_kernel(
    const float* __restrict__ yv, const int* __restrict__ eidx,
    const int* __restrict__ cnt, const int* __restrict__ cur,
    const float* __restrict__ z, const float* __restrict__ b,
    float* __restrict__ out, int n, int doRelu)
{
    int t = blockIdx.x * 256 + threadIdx.x;
    int row = t >> 3, part = t & 7;
    if (row >= n) return;
    int c = cnt[row];
    int beg = cur[row];
    int end = beg + c;
    const float4* y4 = (const float4*)yv;
    float4 acc = make_float4(0.f, 0.f, 0.f, 0.f);
    int e = beg;
    for (; e + 1 < end; e += 2) {
        int s0 = eidx[e], s1 = eidx[e + 1];
        float4 v0 = y4[(long)s0 * 8 + part];
        float4 v1 = y4[(long)s1 * 8 + part];
        acc.x += v0.x + v1.x;
        acc.y += v0.y + v1.y;
        acc.z += v0.z + v1.z;
        acc.w += v0.w + v1.w;
    }
    if (e < end) {
        int s0 = eidx[e];
        float4 v0 = y4[(long)s0 * 8 + part];
        acc.x += v0.x; acc.y += v0.y; acc.z += v0.z; acc.w += v0.w;
    }
    float inv = 1.f / fmaxf((float)c, 1.f);
    float4 bb = ((const float4*)b)[part];
    float4 zz = ((const float4*)z)[(long)row * 8 + part];
    float4 v;
    v.x = fmaf(acc.x, inv, bb.x) + zz.x;
    v.y = fmaf(acc.y, inv, bb.y) + zz.y;
    v.z = fmaf(acc.z, inv, bb.z) + zz.z;
    v.w = fmaf(acc.w, inv, bb.w) + zz.w;
    float ss = v.x * v.x + v.y * v.y + v.z * v.z + v.w * v.w;
    ss += __shfl_xor(ss, 1);
    ss += __shfl_xor(ss, 2);
    ss += __shfl_xor(ss, 4);
    float q = 1.f / fmaxf(sqrtf(ss), 1e-12f);
    v.x *= q; v.y *= q; v.z *= q; v.w *= q;
    if (doRelu) {
        v.x = fmaxf(v.x, 0.f); v.y = fmaxf(v.y, 0.f);
        v.z = fmaxf(v.z, 0.f); v.w = fmaxf(v.w, 0.f);
    }
    ((float4*)out)[(long)row * 8 + part] = v;
}

extern "C" void kernel_launch(void* const* d_in, const int* in_sizes, int n_in,
                              void* d_out, int out_size, void* d_ws, size_t ws_size,
                              hipStream_t stream) {
    const float* x   = (const float*)d_in[0];
    const int* src0  = (const int*)d_in[1];
    const int* tgt0  = (const int*)d_in[2];
    const int* src1  = (const int*)d_in[3];
    const int* tgt1  = (const int*)d_in[4];
    const float* wl0 = (const float*)d_in[5];
    const float* bl0 = (const float*)d_in[6];
    const float* wr0 = (const float*)d_in[7];
    const float* wl1 = (const float*)d_in[8];
    const float* bl1 = (const float*)d_in[9];
    const float* wr1 = (const float*)d_in[10];

    char* W = (char*)d_ws;
    // region A [0,32M): y0; after gather0 reused for layer-1 buffers
    float* y0    = (float*)(W + 0);             // 32 MB
    float* y1    = (float*)(W + 0);             // 16 MB
    float* z1    = (float*)(W + 16777216);      //  8 MB
    int*   eidx1 = (int*)  (W + 25165824);      //  4 MB
    int*   cnt1  = (int*)  (W + 29360128);      // 256 KB
    int*   cur1  = (int*)  (W + 29622272);      // 256 KB
    // region B [32M,48M): z0; after gather0 reused for pairs1 (8 MB)
    float* z0    = (float*)(W + 33554432);      // 16 MB
    int2*  pairs1= (int2*) (W + 33554432);      //  8 MB
    // region C [48M,64M): pairs0 (live P1->P2), then h (written by gather0 after P2)
    int2*  pairs0= (int2*) (W + 50331648);      // 16 MB
    float* h     = (float*)(W + 50331648);      // 16 MB
    // region D [64M,72M): eidx0
    int*   eidx0 = (int*)  (W + 67108864);      //  8 MB
    // region E [72M,...): cnt0, cur0, bsum, bcur
    int*   cnt0  = (int*)  (W + 75497472);      // 512 KB
    int*   cur0  = (int*)  (W + 76021760);      // 512 KB
    int*   bsum  = (int*)  (W + 76546048);      //  1 KB
    int*   bcur  = (int*)  (W + 76547072);      //  1 KB

    // ---- layer 0 ----
    hipMemsetAsync(cnt0, 0, 524288, stream);
    lin0_kernel<<<N0c / 128, 256, 0, stream>>>(x, wl0, wr0, y0, z0);
    hist_kernel<<<E0c / 256, 256, 0, stream>>>(tgt0, cnt0, E0c);
    scanA_kernel<<<N1c / 512, 256, 0, stream>>>(cnt0, cur0, bsum);
    scanB_kernel<<<1, 256, 0, stream>>>(bsum, N1c / 512);
    scanC_kernel<<<N1c / 256, 256, 0, stream>>>(cur0, bsum, bcur);
    part_kernel<<<E0c / 8192, 256, 0, stream>>>(src0, tgt0, pairs0, bcur, 256);
    sortb_kernel<<<N1c / 512, 512, 0, stream>>>(pairs0, cur0, eidx0, N1c, E0c);
    gather_agg_kernel<<<(N1c * 8) / 256, 256, 0, stream>>>(y0, eidx0, cnt0, cur0,
                                                           z0, bl0, h, N1c, 1);

    // ---- layer 1 (y0/z0 dead; regions A/B reused) ----
    hipMemsetAsync(cnt1, 0, 262144, stream);
    hist_kernel<<<E1c / 256, 256, 0, stream>>>(tgt1, cnt1, E1c);
    scanA_kernel<<<N2c / 512, 256, 0, stream>>>(cnt1, cur1, bsum);
    scanB_kernel<<<1, 256, 0, stream>>>(bsum, N2c / 512);
    scanC_kernel<<<N2c / 256, 256, 0, stream>>>(cur1, bsum, bcur);
    part_kernel<<<E1c / 8192, 256, 0, stream>>>(src1, tgt1, pairs1, bcur, 128);
    lin1_kernel<<<N1c / 64, 128, 0, stream>>>(h, wl1, wr1, y1, z1);
    sortb_kernel<<<N2c / 512, 512, 0, stream>>>(pairs1, cur1, eidx1, N2c, E1c);
    gather_agg_kernel<<<(N2c * 8) / 256, 256, 0, stream>>>(y1, eidx1, cnt1, cur1,
                                                           z1, bl1, (float*)d_out, N2c, 0);
}

// Round 6
// 568.065 us; speedup vs baseline: 3.6883x; 3.1787x over previous
//
#include <hip/hip_runtime.h>

#define N0c 262144
#define INc 128
#define Hc  32
#define N1c 131072
#define N2c 65536
#define E0c 2097152
#define E1c 1048576

__device__ __forceinline__ void fma4(float4& a, float s, const float4 w) {
    a.x = fmaf(s, w.x, a.x);
    a.y = fmaf(s, w.y, a.y);
    a.z = fmaf(s, w.z, a.z);
    a.w = fmaf(s, w.w, a.w);
}

// ---------------- layer-0 linear, single-output: out = x @ w^T ----------------
// 256 threads, 128 rows/block, K=128 staged in 4 chunks of 32. LDS 20 KB.
// ONE accumulator set (16 floats) live across barriers -> no spill (rounds 4/5
// spilled GBs with dual Y+Z accumulators live across the 4 staging phases).
__global__ __launch_bounds__(256) void lin0_one_kernel(
    const float* __restrict__ x, const float* __restrict__ w,
    float* __restrict__ out)
{
    __shared__ float xs[128 * 32];     // 16 KB, [row][k-chunk] swizzled
    __shared__ float ws[32 * 32];      //  4 KB, [k][j] swizzled
    const int t = threadIdx.x;
    const int rowBase = blockIdx.x * 128;
    const int cg = t & 7;              // col group (4 cols)
    const int rg = t >> 3;             // row group (4 rows), 0..31

    float4* xs4w = (float4*)xs;
    const float4* xs4 = (const float4*)xs;
    const float4* ws4 = (const float4*)ws;

    float4 acc[4];
#pragma unroll
    for (int i = 0; i < 4; ++i) acc[i] = make_float4(0.f, 0.f, 0.f, 0.f);

    for (int kc = 0; kc < 4; ++kc) {
        if (kc) __syncthreads();
        // stage x chunk: 128 rows x 8 float4, 4 per thread; rotate quad by row>>2
#pragma unroll
        for (int i = 0; i < 4; ++i) {
            int idx = t + 256 * i;
            int row = idx >> 3, kq = idx & 7;
            float4 v = ((const float4*)x)[(rowBase + row) * 32 + kc * 8 + kq];
            xs4w[row * 8 + ((kq + (row >> 2)) & 7)] = v;
        }
        // stage weight chunk: 32 k x 32 j, 4 per thread
#pragma unroll
        for (int i = 0; i < 4; ++i) {
            int idx = t + 256 * i;
            int kk = idx & 31, j = idx >> 5;
            int dst = kk * 32 + 4 * (((j >> 2) + kk) & 7) + (j & 3);
            ws[dst] = w[j * 128 + kc * 32 + kk];
        }
        __syncthreads();

#pragma unroll
        for (int kq = 0; kq < 8; ++kq) {
            float4 xv[4];
#pragma unroll
            for (int i = 0; i < 4; ++i)
                xv[i] = xs4[(4 * rg + i) * 8 + ((kq + rg) & 7)];
            const int kb = 4 * kq;
            float4 w0 = ws4[(kb + 0) * 8 + ((cg + kb + 0) & 7)];
            float4 w1 = ws4[(kb + 1) * 8 + ((cg + kb + 1) & 7)];
            float4 w2 = ws4[(kb + 2) * 8 + ((cg + kb + 2) & 7)];
            float4 w3 = ws4[(kb + 3) * 8 + ((cg + kb + 3) & 7)];
#pragma unroll
            for (int i = 0; i < 4; ++i) {
                fma4(acc[i], xv[i].x, w0);
                fma4(acc[i], xv[i].y, w1);
                fma4(acc[i], xv[i].z, w2);
                fma4(acc[i], xv[i].w, w3);
            }
        }
    }

#pragma unroll
    for (int i = 0; i < 4; ++i) {
        int r = rowBase + 4 * rg + i;
        ((float4*)out)[r * 8 + cg] = acc[i];
    }
}

// ---------------- layer-1 linear: K=32, 64 rows/block (round-3 proven) ----------------
__global__ __launch_bounds__(128) void lin1_kernel(
    const float* __restrict__ h, const float* __restrict__ wl,
    const float* __restrict__ wr, float* __restrict__ y, float* __restrict__ z)
{
    __shared__ float xs[64 * 32];
    __shared__ float wls[32 * 32];
    __shared__ float wrs[32 * 32];
    const int t = threadIdx.x;
    const long rowBase = (long)blockIdx.x * 64;
    const bool doZ = rowBase < N2c;

#pragma unroll
    for (int i = 0; i < 8; ++i) {
        int idx = t + 128 * i;          // = j*32 + k
        int j = idx >> 5, k = idx & 31;
        int dst = k * 32 + 4 * (((j >> 2) + k) & 7) + (j & 3);
        wls[dst] = wl[idx];
        if (doZ) wrs[dst] = wr[idx];
    }
#pragma unroll
    for (int i = 0; i < 4; ++i) {
        int idx = t + 128 * i;          // float4 idx 0..511
        int row = idx >> 3, k4 = idx & 7;
        float4 v = ((const float4*)h)[rowBase * 8 + idx];
        ((float4*)xs)[row * 8 + ((k4 + (row >> 2)) & 7)] = v;
    }
    __syncthreads();

    const int cg = t & 7;
    const int rg = t >> 3;
    const float4* xs4  = (const float4*)xs;
    const float4* wls4 = (const float4*)wls;
    const float4* wrs4 = (const float4*)wrs;

    float4 accY[4], accZ[4];
#pragma unroll
    for (int i = 0; i < 4; ++i) {
        accY[i] = make_float4(0.f, 0.f, 0.f, 0.f);
        accZ[i] = make_float4(0.f, 0.f, 0.f, 0.f);
    }

#pragma unroll
    for (int k4 = 0; k4 < 8; ++k4) {
        float4 xv[4];
#pragma unroll
        for (int i = 0; i < 4; ++i)
            xv[i] = xs4[(4 * rg + i) * 8 + ((k4 + rg) & 7)];
        const int kb = 4 * k4;
        float4 w0 = wls4[(kb + 0) * 8 + ((cg + kb + 0) & 7)];
        float4 w1 = wls4[(kb + 1) * 8 + ((cg + kb + 1) & 7)];
        float4 w2 = wls4[(kb + 2) * 8 + ((cg + kb + 2) & 7)];
        float4 w3 = wls4[(kb + 3) * 8 + ((cg + kb + 3) & 7)];
#pragma unroll
        for (int i = 0; i < 4; ++i) {
            fma4(accY[i], xv[i].x, w0);
            fma4(accY[i], xv[i].y, w1);
            fma4(accY[i], xv[i].z, w2);
            fma4(accY[i], xv[i].w, w3);
        }
        if (doZ) {
            float4 u0 = wrs4[(kb + 0) * 8 + ((cg + kb + 0) & 7)];
            float4 u1 = wrs4[(kb + 1) * 8 + ((cg + kb + 1) & 7)];
            float4 u2 = wrs4[(kb + 2) * 8 + ((cg + kb + 2) & 7)];
            float4 u3 = wrs4[(kb + 3) * 8 + ((cg + kb + 3) & 7)];
#pragma unroll
            for (int i = 0; i < 4; ++i) {
                fma4(accZ[i], xv[i].x, u0);
                fma4(accZ[i], xv[i].y, u1);
                fma4(accZ[i], xv[i].z, u2);
                fma4(accZ[i], xv[i].w, u3);
            }
        }
    }
#pragma unroll
    for (int i = 0; i < 4; ++i) {
        long r = rowBase + 4 * rg + i;
        ((float4*)y)[r * 8 + cg] = accY[i];
        if (doZ) ((float4*)z)[r * 8 + cg] = accZ[i];
    }
}

// ---------------- CSR build: per-target histogram ----------------
__global__ __launch_bounds__(256) void hist_kernel(
    const int* __restrict__ tgt, int* __restrict__ cnt, int nE)
{
    int e = blockIdx.x * 256 + threadIdx.x;
    if (e < nE) atomicAdd(&cnt[tgt[e]], 1);
}

// ---------------- CSR build: 2-level exclusive scan ----------------
__global__ __launch_bounds__(256) void scanA_kernel(
    const int* __restrict__ cnt, int* __restrict__ cursor, int* __restrict__ bsum)
{
    __shared__ int s[256];
    int t = threadIdx.x;
    int base = blockIdx.x * 512;
    int c0 = cnt[base + 2 * t];
    int c1 = cnt[base + 2 * t + 1];
    int local = c0 + c1;
    s[t] = local;
    __syncthreads();
    int v = local;
#pragma unroll
    for (int off = 1; off < 256; off <<= 1) {
        int u = (t >= off) ? s[t - off] : 0;
        __syncthreads();
        v += u;
        s[t] = v;
        __syncthreads();
    }
    int ex = v - local;
    cursor[base + 2 * t]     = ex;
    cursor[base + 2 * t + 1] = ex + c0;
    if (t == 255) bsum[blockIdx.x] = v;
}

__global__ __launch_bounds__(256) void scanB_kernel(int* __restrict__ bsum, int nb)
{
    __shared__ int s[256];
    int t = threadIdx.x;
    int local = (t < nb) ? bsum[t] : 0;
    s[t] = local;
    __syncthreads();
    int v = local;
#pragma unroll
    for (int off = 1; off < 256; off <<= 1) {
        int u = (t >= off) ? s[t - off] : 0;
        __syncthreads();
        v += u;
        s[t] = v;
        __syncthreads();
    }
    if (t < nb) bsum[t] = v - local;
}

// scanC: add block offsets; also emit per-bucket (512-target group) base cursors
__global__ __launch_bounds__(256) void scanC_kernel(
    int* __restrict__ cursor, const int* __restrict__ bsum, int* __restrict__ bcur)
{
    int i = blockIdx.x * 256 + threadIdx.x;
    int v = cursor[i] + bsum[i >> 9];
    cursor[i] = v;
    if ((i & 511) == 0) bcur[i >> 9] = v;
}

// ---------------- partition pass 1: multisplit into 512-target buckets ----------------
__global__ __launch_bounds__(256) void part_kernel(
    const int* __restrict__ src, const int* __restrict__ tgt,
    int2* __restrict__ pairs, int* __restrict__ bcur, int nb)
{
    __shared__ int hist[256];
    __shared__ int bbase[256];
    const int t = threadIdx.x;
    const int base = blockIdx.x * 8192;
    hist[t] = 0;
    __syncthreads();
#pragma unroll 4
    for (int i = 0; i < 32; ++i) {
        int e = base + i * 256 + t;
        atomicAdd(&hist[tgt[e] >> 9], 1);
    }
    __syncthreads();
    if (t < nb) bbase[t] = atomicAdd(&bcur[t], hist[t]);
    __syncthreads();
    hist[t] = 0;
    __syncthreads();
#pragma unroll 4
    for (int i = 0; i < 32; ++i) {
        int e = base + i * 256 + t;
        int tv = tgt[e], sv = src[e];
        int b = tv >> 9;
        int r = atomicAdd(&hist[b], 1);
        pairs[bbase[b] + r] = make_int2(sv, tv);
    }
}

// ---------------- partition pass 2: bucket-local rank -> eidx ----------------
__global__ __launch_bounds__(512) void sortb_kernel(
    const int2* __restrict__ pairs, const int* __restrict__ cur,
    int* __restrict__ eidx, int nT, int nE)
{
    __shared__ int lrank[512];
    const int b = blockIdx.x;
    const int t = threadIdx.x;
    lrank[t] = 0;
    __syncthreads();
    const int tlo = b << 9;
    const int beg = cur[tlo];
    const int thi = tlo + 512;
    const int end = (thi < nT) ? cur[thi] : nE;
    for (int e = beg + t; e < end; e += 512) {
        int2 p = pairs[e];
        int r = atomicAdd(&lrank[p.y - tlo], 1);
        eidx[cur[p.y] + r] = p.x;
    }
}

// ---------------- gather-reduce + fused epilogue ----------------
__global__ __launch_bounds__(256) void gather_agg_kernel(
    const float* __restrict__ yv, const int* __restrict__ eidx,
    const int* __restrict__ cnt, const int* __restrict__ cur,
    const float* __restrict__ z, const float* __restrict__ b,
    float* __restrict__ out, int n, int doRelu)
{
    int t = blockIdx.x * 256 + threadIdx.x;
    int row = t >> 3, part = t & 7;
    if (row >= n) return;
    int c = cnt[row];
    int beg = cur[row];
    int end = beg + c;
    const float4* y4 = (const float4*)yv;
    float4 acc = make_float4(0.f, 0.f, 0.f, 0.f);
    int e = beg;
    for (; e + 1 < end; e += 2) {
        int s0 = eidx[e], s1 = eidx[e + 1];
        float4 v0 = y4[(long)s0 * 8 + part];
        float4 v1 = y4[(long)s1 * 8 + part];
        acc.x += v0.x + v1.x;
        acc.y += v0.y + v1.y;
        acc.z += v0.z + v1.z;
        acc.w += v0.w + v1.w;
    }
    if (e < end) {
        int s0 = eidx[e];
        float4 v0 = y4[(long)s0 * 8 + part];
        acc.x += v0.x; acc.y += v0.y; acc.z += v0.z; acc.w += v0.w;
    }
    float inv = 1.f / fmaxf((float)c, 1.f);
    float4 bb = ((const float4*)b)[part];
    float4 zz = ((const float4*)z)[(long)row * 8 + part];
    float4 v;
    v.x = fmaf(acc.x, inv, bb.x) + zz.x;
    v.y = fmaf(acc.y, inv, bb.y) + zz.y;
    v.z = fmaf(acc.z, inv, bb.z) + zz.z;
    v.w = fmaf(acc.w, inv, bb.w) + zz.w;
    float ss = v.x * v.x + v.y * v.y + v.z * v.z + v.w * v.w;
    ss += __shfl_xor(ss, 1);
    ss += __shfl_xor(ss, 2);
    ss += __shfl_xor(ss, 4);
    float q = 1.f / fmaxf(sqrtf(ss), 1e-12f);
    v.x *= q; v.y *= q; v.z *= q; v.w *= q;
    if (doRelu) {
        v.x = fmaxf(v.x, 0.f); v.y = fmaxf(v.y, 0.f);
        v.z = fmaxf(v.z, 0.f); v.w = fmaxf(v.w, 0.f);
    }
    ((float4*)out)[(long)row * 8 + part] = v;
}

extern "C" void kernel_launch(void* const* d_in, const int* in_sizes, int n_in,
                              void* d_out, int out_size, void* d_ws, size_t ws_size,
                              hipStream_t stream) {
    const float* x   = (const float*)d_in[0];
    const int* src0  = (const int*)d_in[1];
    const int* tgt0  = (const int*)d_in[2];
    const int* src1  = (const int*)d_in[3];
    const int* tgt1  = (const int*)d_in[4];
    const float* wl0 = (const float*)d_in[5];
    const float* bl0 = (const float*)d_in[6];
    const float* wr0 = (const float*)d_in[7];
    const float* wl1 = (const float*)d_in[8];
    const float* bl1 = (const float*)d_in[9];
    const float* wr1 = (const float*)d_in[10];

    char* W = (char*)d_ws;
    // region A [0,32M): y0; after gather0 reused for layer-1 buffers
    float* y0    = (float*)(W + 0);             // 32 MB
    float* y1    = (float*)(W + 0);             // 16 MB
    float* z1    = (float*)(W + 16777216);      //  8 MB
    int*   eidx1 = (int*)  (W + 25165824);      //  4 MB
    int*   cnt1  = (int*)  (W + 29360128);      // 256 KB
    int*   cur1  = (int*)  (W + 29622272);      // 256 KB
    // region B [32M,48M): z0; after gather0 reused for pairs1 (8 MB)
    float* z0    = (float*)(W + 33554432);      // 16 MB
    int2*  pairs1= (int2*) (W + 33554432);      //  8 MB
    // region C [48M,64M): pairs0 (live P1->P2), then h (written by gather0 after P2)
    int2*  pairs0= (int2*) (W + 50331648);      // 16 MB
    float* h     = (float*)(W + 50331648);      // 16 MB
    // region D [64M,72M): eidx0
    int*   eidx0 = (int*)  (W + 67108864);      //  8 MB
    // region E [72M,...): cnt0, cur0, bsum, bcur
    int*   cnt0  = (int*)  (W + 75497472);      // 512 KB
    int*   cur0  = (int*)  (W + 76021760);      // 512 KB
    int*   bsum  = (int*)  (W + 76546048);      //  1 KB
    int*   bcur  = (int*)  (W + 76547072);      //  1 KB

    // ---- layer 0 ----
    hipMemsetAsync(cnt0, 0, 524288, stream);
    lin0_one_kernel<<<N0c / 128, 256, 0, stream>>>(x, wl0, y0);
    lin0_one_kernel<<<N1c / 128, 256, 0, stream>>>(x, wr0, z0);
    hist_kernel<<<E0c / 256, 256, 0, stream>>>(tgt0, cnt0, E0c);
    scanA_kernel<<<N1c / 512, 256, 0, stream>>>(cnt0, cur0, bsum);
    scanB_kernel<<<1, 256, 0, stream>>>(bsum, N1c / 512);
    scanC_kernel<<<N1c / 256, 256, 0, stream>>>(cur0, bsum, bcur);
    part_kernel<<<E0c / 8192, 256, 0, stream>>>(src0, tgt0, pairs0, bcur, 256);
    sortb_kernel<<<N1c / 512, 512, 0, stream>>>(pairs0, cur0, eidx0, N1c, E0c);
    gather_agg_kernel<<<(N1c * 8) / 256, 256, 0, stream>>>(y0, eidx0, cnt0, cur0,
                                                           z0, bl0, h, N1c, 1);

    // ---- layer 1 (y0/z0 dead; regions A/B reused) ----
    hipMemsetAsync(cnt1, 0, 262144, stream);
    hist_kernel<<<E1c / 256, 256, 0, stream>>>(tgt1, cnt1, E1c);
    scanA_kernel<<<N2c / 512, 256, 0, stream>>>(cnt1, cur1, bsum);
    scanB_kernel<<<1, 256, 0, stream>>>(bsum, N2c / 512);
    scanC_kernel<<<N2c / 256, 256, 0, stream>>>(cur1, bsum, bcur);
    part_kernel<<<E1c / 8192, 256, 0, stream>>>(src1, tgt1, pairs1, bcur, 128);
    lin1_kernel<<<N1c / 64, 128, 0, stream>>>(h, wl1, wr1, y1, z1);
    sortb_kernel<<<N2c / 512, 512, 0, stream>>>(pairs1, cur1, eidx1, N2c, E1c);
    gather_agg_kernel<<<(N2c * 8) / 256, 256, 0, stream>>>(y1, eidx1, cnt1, cur1,
                                                           z1, bl1, (float*)d_out, N2c, 0);
}

// Round 7
// 465.390 us; speedup vs baseline: 4.5020x; 1.2206x over previous
//
#include <hip/hip_runtime.h>

#define N0c 262144
#define INc 128
#define Hc  32
#define N1c 131072
#define N2c 65536
#define E0c 2097152
#define E1c 1048576

__device__ __forceinline__ void fma4(float4& a, float s, const float4 w) {
    a.x = fmaf(s, w.x, a.x);
    a.y = fmaf(s, w.y, a.y);
    a.z = fmaf(s, w.z, a.z);
    a.w = fmaf(s, w.w, a.w);
}

// ---------------- layer-0 linear, single-output: out = x @ w^T ----------------
// 256 threads, 128 rows/block, K=128 in 4 chunks. LDS 20 KB, one acc set -> no spill.
__global__ __launch_bounds__(256) void lin0_one_kernel(
    const float* __restrict__ x, const float* __restrict__ w,
    float* __restrict__ out)
{
    __shared__ float xs[128 * 32];
    __shared__ float ws[32 * 32];
    const int t = threadIdx.x;
    const int rowBase = blockIdx.x * 128;
    const int cg = t & 7;
    const int rg = t >> 3;

    float4* xs4w = (float4*)xs;
    const float4* xs4 = (const float4*)xs;
    const float4* ws4 = (const float4*)ws;

    float4 acc[4];
#pragma unroll
    for (int i = 0; i < 4; ++i) acc[i] = make_float4(0.f, 0.f, 0.f, 0.f);

    for (int kc = 0; kc < 4; ++kc) {
        if (kc) __syncthreads();
#pragma unroll
        for (int i = 0; i < 4; ++i) {
            int idx = t + 256 * i;
            int row = idx >> 3, kq = idx & 7;
            float4 v = ((const float4*)x)[(rowBase + row) * 32 + kc * 8 + kq];
            xs4w[row * 8 + ((kq + (row >> 2)) & 7)] = v;
        }
#pragma unroll
        for (int i = 0; i < 4; ++i) {
            int idx = t + 256 * i;
            int kk = idx & 31, j = idx >> 5;
            int dst = kk * 32 + 4 * (((j >> 2) + kk) & 7) + (j & 3);
            ws[dst] = w[j * 128 + kc * 32 + kk];
        }
        __syncthreads();

#pragma unroll
        for (int kq = 0; kq < 8; ++kq) {
            float4 xv[4];
#pragma unroll
            for (int i = 0; i < 4; ++i)
                xv[i] = xs4[(4 * rg + i) * 8 + ((kq + rg) & 7)];
            const int kb = 4 * kq;
            float4 w0 = ws4[(kb + 0) * 8 + ((cg + kb + 0) & 7)];
            float4 w1 = ws4[(kb + 1) * 8 + ((cg + kb + 1) & 7)];
            float4 w2 = ws4[(kb + 2) * 8 + ((cg + kb + 2) & 7)];
            float4 w3 = ws4[(kb + 3) * 8 + ((cg + kb + 3) & 7)];
#pragma unroll
            for (int i = 0; i < 4; ++i) {
                fma4(acc[i], xv[i].x, w0);
                fma4(acc[i], xv[i].y, w1);
                fma4(acc[i], xv[i].z, w2);
                fma4(acc[i], xv[i].w, w3);
            }
        }
    }

#pragma unroll
    for (int i = 0; i < 4; ++i) {
        int r = rowBase + 4 * rg + i;
        ((float4*)out)[r * 8 + cg] = acc[i];
    }
}

// ---------------- layer-1 linear: K=32, 64 rows/block ----------------
__global__ __launch_bounds__(128) void lin1_kernel(
    const float* __restrict__ h, const float* __restrict__ wl,
    const float* __restrict__ wr, float* __restrict__ y, float* __restrict__ z)
{
    __shared__ float xs[64 * 32];
    __shared__ float wls[32 * 32];
    __shared__ float wrs[32 * 32];
    const int t = threadIdx.x;
    const long rowBase = (long)blockIdx.x * 64;
    const bool doZ = rowBase < N2c;

#pragma unroll
    for (int i = 0; i < 8; ++i) {
        int idx = t + 128 * i;
        int j = idx >> 5, k = idx & 31;
        int dst = k * 32 + 4 * (((j >> 2) + k) & 7) + (j & 3);
        wls[dst] = wl[idx];
        if (doZ) wrs[dst] = wr[idx];
    }
#pragma unroll
    for (int i = 0; i < 4; ++i) {
        int idx = t + 128 * i;
        int row = idx >> 3, k4 = idx & 7;
        float4 v = ((const float4*)h)[rowBase * 8 + idx];
        ((float4*)xs)[row * 8 + ((k4 + (row >> 2)) & 7)] = v;
    }
    __syncthreads();

    const int cg = t & 7;
    const int rg = t >> 3;
    const float4* xs4  = (const float4*)xs;
    const float4* wls4 = (const float4*)wls;
    const float4* wrs4 = (const float4*)wrs;

    float4 accY[4], accZ[4];
#pragma unroll
    for (int i = 0; i < 4; ++i) {
        accY[i] = make_float4(0.f, 0.f, 0.f, 0.f);
        accZ[i] = make_float4(0.f, 0.f, 0.f, 0.f);
    }

#pragma unroll
    for (int k4 = 0; k4 < 8; ++k4) {
        float4 xv[4];
#pragma unroll
        for (int i = 0; i < 4; ++i)
            xv[i] = xs4[(4 * rg + i) * 8 + ((k4 + rg) & 7)];
        const int kb = 4 * k4;
        float4 w0 = wls4[(kb + 0) * 8 + ((cg + kb + 0) & 7)];
        float4 w1 = wls4[(kb + 1) * 8 + ((cg + kb + 1) & 7)];
        float4 w2 = wls4[(kb + 2) * 8 + ((cg + kb + 2) & 7)];
        float4 w3 = wls4[(kb + 3) * 8 + ((cg + kb + 3) & 7)];
#pragma unroll
        for (int i = 0; i < 4; ++i) {
            fma4(accY[i], xv[i].x, w0);
            fma4(accY[i], xv[i].y, w1);
            fma4(accY[i], xv[i].z, w2);
            fma4(accY[i], xv[i].w, w3);
        }
        if (doZ) {
            float4 u0 = wrs4[(kb + 0) * 8 + ((cg + kb + 0) & 7)];
            float4 u1 = wrs4[(kb + 1) * 8 + ((cg + kb + 1) & 7)];
            float4 u2 = wrs4[(kb + 2) * 8 + ((cg + kb + 2) & 7)];
            float4 u3 = wrs4[(kb + 3) * 8 + ((cg + kb + 3) & 7)];
#pragma unroll
            for (int i = 0; i < 4; ++i) {
                fma4(accZ[i], xv[i].x, u0);
                fma4(accZ[i], xv[i].y, u1);
                fma4(accZ[i], xv[i].z, u2);
                fma4(accZ[i], xv[i].w, u3);
            }
        }
    }
#pragma unroll
    for (int i = 0; i < 4; ++i) {
        long r = rowBase + 4 * rg + i;
        ((float4*)y)[r * 8 + cg] = accY[i];
        if (doZ) ((float4*)z)[r * 8 + cg] = accZ[i];
    }
}

// ---------------- bucket histogram: LDS per-block, 256 atomics/block ----------------
// Replaces the 2M-scattered-atomic per-target hist (82 us, 65 MB write-through).
__global__ __launch_bounds__(256) void bhist_kernel(
    const int* __restrict__ tgt, int* __restrict__ bcnt, int nb)
{
    __shared__ int hist[256];
    const int t = threadIdx.x;
    const int base = blockIdx.x * 8192;
    hist[t] = 0;
    __syncthreads();
#pragma unroll 4
    for (int i = 0; i < 32; ++i)
        atomicAdd(&hist[tgt[base + i * 256 + t] >> 9], 1);
    __syncthreads();
    if (t < nb && hist[t]) atomicAdd(&bcnt[t], hist[t]);
}

// ---------------- bucket scan: one block, exclusive scan of nb bucket counts ----------------
__global__ __launch_bounds__(256) void bscan_kernel(
    const int* __restrict__ bcnt, int* __restrict__ bbase,
    int* __restrict__ bcur, int nb, int nE)
{
    __shared__ int s[256];
    int t = threadIdx.x;
    int local = (t < nb) ? bcnt[t] : 0;
    s[t] = local;
    __syncthreads();
    int v = local;
#pragma unroll
    for (int off = 1; off < 256; off <<= 1) {
        int u = (t >= off) ? s[t - off] : 0;
        __syncthreads();
        v += u;
        s[t] = v;
        __syncthreads();
    }
    int ex = v - local;
    if (t < nb) {
        bbase[t] = ex;
        bcur[t] = ex;
    }
    if (t == nb - 1) bbase[nb] = nE;
}

// ---------------- partition pass 1: multisplit into 512-target buckets ----------------
__global__ __launch_bounds__(256) void part_kernel(
    const int* __restrict__ src, const int* __restrict__ tgt,
    int2* __restrict__ pairs, int* __restrict__ bcur, int nb)
{
    __shared__ int hist[256];
    __shared__ int bbase[256];
    const int t = threadIdx.x;
    const int base = blockIdx.x * 8192;
    hist[t] = 0;
    __syncthreads();
#pragma unroll 4
    for (int i = 0; i < 32; ++i) {
        int e = base + i * 256 + t;
        atomicAdd(&hist[tgt[e] >> 9], 1);
    }
    __syncthreads();
    if (t < nb) bbase[t] = atomicAdd(&bcur[t], hist[t]);
    __syncthreads();
    hist[t] = 0;
    __syncthreads();
#pragma unroll 4
    for (int i = 0; i < 32; ++i) {
        int e = base + i * 256 + t;
        int tv = tgt[e], sv = src[e];
        int b = tv >> 9;
        int r = atomicAdd(&hist[b], 1);
        pairs[bbase[b] + r] = make_int2(sv, tv);
    }
}

// ---------------- partition pass 2: per-bucket count + scan + rank -> cnt, cur, eidx ----
// One block per bucket of 512 targets. All per-target state LDS-local.
__global__ __launch_bounds__(512) void sortb_kernel(
    const int2* __restrict__ pairs, const int* __restrict__ bbase,
    int* __restrict__ cnt, int* __restrict__ cur, int* __restrict__ eidx)
{
    __shared__ int cl[512];      // counts, then rank counters
    __shared__ int offs[512];    // scan workspace, then absolute bases
    const int b = blockIdx.x;
    const int t = threadIdx.x;
    const int tlo = b << 9;
    const int beg = bbase[b];
    const int end = bbase[b + 1];

    cl[t] = 0;
    __syncthreads();
    for (int e = beg + t; e < end; e += 512)
        atomicAdd(&cl[pairs[e].y - tlo], 1);
    __syncthreads();
    int local = cl[t];
    offs[t] = local;
    __syncthreads();
    int v = local;
#pragma unroll
    for (int off = 1; off < 512; off <<= 1) {
        int u = (t >= off) ? offs[t - off] : 0;
        __syncthreads();
        v += u;
        offs[t] = v;
        __syncthreads();
    }
    int ex = v - local;
    cnt[tlo + t] = local;
    cur[tlo + t] = beg + ex;
    __syncthreads();
    offs[t] = beg + ex;          // absolute base per target
    cl[t] = 0;                   // reuse as rank
    __syncthreads();
    for (int e = beg + t; e < end; e += 512) {
        int2 p = pairs[e];
        int li = p.y - tlo;
        int r = atomicAdd(&cl[li], 1);
        eidx[offs[li] + r] = p.x;
    }
}

// ---------------- gather-reduce + fused epilogue ----------------
__global__ __launch_bounds__(256) void gather_agg_kernel(
    const float* __restrict__ yv, const int* __restrict__ eidx,
    const int* __restrict__ cnt, const int* __restrict__ cur,
    const float* __restrict__ z, const float* __restrict__ b,
    float* __restrict__ out, int n, int doRelu)
{
    int t = blockIdx.x * 256 + threadIdx.x;
    int row = t >> 3, part = t & 7;
    if (row >= n) return;
    int c = cnt[row];
    int beg = cur[row];
    int end = beg + c;
    const float4* y4 = (const float4*)yv;
    float4 acc = make_float4(0.f, 0.f, 0.f, 0.f);
    int e = beg;
    for (; e + 1 < end; e += 2) {
        int s0 = eidx[e], s1 = eidx[e + 1];
        float4 v0 = y4[(long)s0 * 8 + part];
        float4 v1 = y4[(long)s1 * 8 + part];
        acc.x += v0.x + v1.x;
        acc.y += v0.y + v1.y;
        acc.z += v0.z + v1.z;
        acc.w += v0.w + v1.w;
    }
    if (e < end) {
        int s0 = eidx[e];
        float4 v0 = y4[(long)s0 * 8 + part];
        acc.x += v0.x; acc.y += v0.y; acc.z += v0.z; acc.w += v0.w;
    }
    float inv = 1.f / fmaxf((float)c, 1.f);
    float4 bb = ((const float4*)b)[part];
    float4 zz = ((const float4*)z)[(long)row * 8 + part];
    float4 v;
    v.x = fmaf(acc.x, inv, bb.x) + zz.x;
    v.y = fmaf(acc.y, inv, bb.y) + zz.y;
    v.z = fmaf(acc.z, inv, bb.z) + zz.z;
    v.w = fmaf(acc.w, inv, bb.w) + zz.w;
    float ss = v.x * v.x + v.y * v.y + v.z * v.z + v.w * v.w;
    ss += __shfl_xor(ss, 1);
    ss += __shfl_xor(ss, 2);
    ss += __shfl_xor(ss, 4);
    float q = 1.f / fmaxf(sqrtf(ss), 1e-12f);
    v.x *= q; v.y *= q; v.z *= q; v.w *= q;
    if (doRelu) {
        v.x = fmaxf(v.x, 0.f); v.y = fmaxf(v.y, 0.f);
        v.z = fmaxf(v.z, 0.f); v.w = fmaxf(v.w, 0.f);
    }
    ((float4*)out)[(long)row * 8 + part] = v;
}

extern "C" void kernel_launch(void* const* d_in, const int* in_sizes, int n_in,
                              void* d_out, int out_size, void* d_ws, size_t ws_size,
                              hipStream_t stream) {
    const float* x   = (const float*)d_in[0];
    const int* src0  = (const int*)d_in[1];
    const int* tgt0  = (const int*)d_in[2];
    const int* src1  = (const int*)d_in[3];
    const int* tgt1  = (const int*)d_in[4];
    const float* wl0 = (const float*)d_in[5];
    const float* bl0 = (const float*)d_in[6];
    const float* wr0 = (const float*)d_in[7];
    const float* wl1 = (const float*)d_in[8];
    const float* bl1 = (const float*)d_in[9];
    const float* wr1 = (const float*)d_in[10];

    char* W = (char*)d_ws;
    // region A [0,32M): y0; after gather0 reused for layer-1 buffers
    float* y0    = (float*)(W + 0);             // 32 MB
    float* y1    = (float*)(W + 0);             // 16 MB
    float* z1    = (float*)(W + 16777216);      //  8 MB
    int*   eidx1 = (int*)  (W + 25165824);      //  4 MB
    int*   cnt1  = (int*)  (W + 29360128);      // 256 KB
    int*   cur1  = (int*)  (W + 29622272);      // 256 KB
    // region B [32M,48M): z0; after gather0 reused for pairs1 (8 MB)
    float* z0    = (float*)(W + 33554432);      // 16 MB
    int2*  pairs1= (int2*) (W + 33554432);      //  8 MB
    // region C [48M,64M): pairs0 (live P1->P2), then h (written by gather0)
    int2*  pairs0= (int2*) (W + 50331648);      // 16 MB
    float* h     = (float*)(W + 50331648);      // 16 MB
    // region D [64M,72M): eidx0
    int*   eidx0 = (int*)  (W + 67108864);      //  8 MB
    // region E [72M,...): cnt0, cur0, bucket scratch
    int*   cnt0  = (int*)  (W + 75497472);      // 512 KB
    int*   cur0  = (int*)  (W + 76021760);      // 512 KB
    int*   bcnt  = (int*)  (W + 76546048);      //  1 KB
    int*   bbase = (int*)  (W + 76547072);      //  2 KB (257 ints)
    int*   bcur  = (int*)  (W + 76549120);      //  1 KB

    // ---- layer 0 ----
    hipMemsetAsync(bcnt, 0, 1024, stream);
    lin0_one_kernel<<<N0c / 128, 256, 0, stream>>>(x, wl0, y0);
    lin0_one_kernel<<<N1c / 128, 256, 0, stream>>>(x, wr0, z0);
    bhist_kernel<<<E0c / 8192, 256, 0, stream>>>(tgt0, bcnt, 256);
    bscan_kernel<<<1, 256, 0, stream>>>(bcnt, bbase, bcur, 256, E0c);
    part_kernel<<<E0c / 8192, 256, 0, stream>>>(src0, tgt0, pairs0, bcur, 256);
    sortb_kernel<<<N1c / 512, 512, 0, stream>>>(pairs0, bbase, cnt0, cur0, eidx0);
    gather_agg_kernel<<<(N1c * 8) / 256, 256, 0, stream>>>(y0, eidx0, cnt0, cur0,
                                                           z0, bl0, h, N1c, 1);

    // ---- layer 1 (y0/z0 dead; regions A/B reused) ----
    hipMemsetAsync(bcnt, 0, 1024, stream);
    bhist_kernel<<<E1c / 8192, 256, 0, stream>>>(tgt1, bcnt, 128);
    bscan_kernel<<<1, 256, 0, stream>>>(bcnt, bbase, bcur, 128, E1c);
    part_kernel<<<E1c / 8192, 256, 0, stream>>>(src1, tgt1, pairs1, bcur, 128);
    lin1_kernel<<<N1c / 64, 128, 0, stream>>>(h, wl1, wr1, y1, z1);
    sortb_kernel<<<N2c / 512, 512, 0, stream>>>(pairs1, bbase, cnt1, cur1, eidx1);
    gather_agg_kernel<<<(N2c * 8) / 256, 256, 0, stream>>>(y1, eidx1, cnt1, cur1,
                                                           z1, bl1, (float*)d_out, N2c, 0);
}